// Round 1
// baseline (493.118 us; speedup 1.0000x reference)
//
#include <hip/hip_runtime.h>

#define N_CLASSES 128

// One 32-lane group per row. Lane j loads float4 j of the 128-float row
// (32 lanes x 16B = 512B contiguous per input). Single pass:
//   loss = (m + log(sum exp(yh - m))) * sum(y) - sum(y * yh)
// argmax(y) with first-occurrence tie-break selects the class bin.
__global__ __launch_bounds__(256) void class_loss_kernel(
    const float* __restrict__ y_hat,
    const float* __restrict__ y,
    float* __restrict__ ws,   // [0..127] class sums, [128..255] class counts
    int B)
{
    __shared__ float s_sum[N_CLASSES];
    __shared__ float s_cnt[N_CLASSES];
    const int tid = threadIdx.x;
    for (int i = tid; i < N_CLASSES; i += blockDim.x) { s_sum[i] = 0.f; s_cnt[i] = 0.f; }
    __syncthreads();

    const int lane    = tid & 31;                                  // lane within row-group
    const int group   = (blockIdx.x * blockDim.x + tid) >> 5;      // global row-group id
    const int ngroups = (gridDim.x * blockDim.x) >> 5;

    for (int row = group; row < B; row += ngroups) {
        const float4 h4 = ((const float4*)(y_hat + (size_t)row * N_CLASSES))[lane];
        const float4 t4 = ((const float4*)(y     + (size_t)row * N_CLASSES))[lane];

        // row max of y_hat (keep h4 in registers for the exp pass)
        float m = fmaxf(fmaxf(h4.x, h4.y), fmaxf(h4.z, h4.w));
        #pragma unroll
        for (int o = 16; o >= 1; o >>= 1) m = fmaxf(m, __shfl_xor(m, o, 32));

        // partials: sum exp, dot(y, y_hat), sum y
        float s   = __expf(h4.x - m) + __expf(h4.y - m) + __expf(h4.z - m) + __expf(h4.w - m);
        float dot = t4.x * h4.x + t4.y * h4.y + t4.z * h4.z + t4.w * h4.w;
        float sy  = t4.x + t4.y + t4.z + t4.w;

        // argmax(y), first occurrence wins ties
        float bv = t4.x; int bi = lane * 4;
        if (t4.y > bv) { bv = t4.y; bi = lane * 4 + 1; }
        if (t4.z > bv) { bv = t4.z; bi = lane * 4 + 2; }
        if (t4.w > bv) { bv = t4.w; bi = lane * 4 + 3; }

        #pragma unroll
        for (int o = 16; o >= 1; o >>= 1) {
            s   += __shfl_xor(s,   o, 32);
            dot += __shfl_xor(dot, o, 32);
            sy  += __shfl_xor(sy,  o, 32);
            float ov = __shfl_xor(bv, o, 32);
            int   oi = __shfl_xor(bi, o, 32);
            if (ov > bv || (ov == bv && oi < bi)) { bv = ov; bi = oi; }
        }

        if (lane == 0) {
            float loss = (m + __logf(s)) * sy - dot;
            atomicAdd(&s_sum[bi], loss);
            atomicAdd(&s_cnt[bi], 1.0f);
        }
    }

    __syncthreads();
    for (int i = tid; i < N_CLASSES; i += blockDim.x) {
        if (s_cnt[i] > 0.f) {
            atomicAdd(&ws[i], s_sum[i]);
            atomicAdd(&ws[N_CLASSES + i], s_cnt[i]);
        }
    }
}

__global__ void finalize_kernel(const float* __restrict__ ws, float* __restrict__ out) {
    const int c = threadIdx.x;
    if (c < N_CLASSES) {
        float cnt = ws[N_CLASSES + c];
        out[c] = (cnt > 0.f) ? ws[c] / cnt : 0.0f;
    }
}

extern "C" void kernel_launch(void* const* d_in, const int* in_sizes, int n_in,
                              void* d_out, int out_size, void* d_ws, size_t ws_size,
                              hipStream_t stream) {
    const float* y_hat = (const float*)d_in[0];
    const float* y     = (const float*)d_in[1];
    float* ws  = (float*)d_ws;
    float* out = (float*)d_out;
    const int B = in_sizes[0] / N_CLASSES;

    hipMemsetAsync(d_ws, 0, 2 * N_CLASSES * sizeof(float), stream);

    const int blocks = 1024;  // 8192 row-groups; ~61 rows each at B=500k
    class_loss_kernel<<<blocks, 256, 0, stream>>>(y_hat, y, ws, B);
    finalize_kernel<<<1, N_CLASSES, 0, stream>>>(ws, out);
}